// Round 12
// baseline (4625.354 us; speedup 1.0000x reference)
//
#include <hip/hip_runtime.h>
#include <hip/hip_bf16.h>

// ---------------- block reduction ----------------
template<int NT>
__device__ __forceinline__ float block_sum(float v, float* red, int t) {
  red[t] = v; __syncthreads();
#pragma unroll
  for (int s = NT/2; s > 0; s >>= 1) {
    if (t < s) red[t] += red[t+s];
    __syncthreads();
  }
  float r = red[0];
  __syncthreads();
  return r;
}

// dot of an f32 row (length DIN, mult of 4) against f32 shared vector
template<int DIN>
__device__ __forceinline__ float dot_f32_row(const float* __restrict__ wr, const float* __restrict__ xs) {
  float acc = 0.f;
  const float4* wp = reinterpret_cast<const float4*>(wr);
#pragma unroll 4
  for (int i = 0; i < DIN/4; ++i) {
    float4 w4 = wp[i];
    acc += w4.x*xs[i*4] + w4.y*xs[i*4+1] + w4.z*xs[i*4+2] + w4.w*xs[i*4+3];
  }
  return acc;
}

// ---------------- conv1: 3->64, 32x32, BN+ReLU+maxpool2 -> [512,64,16,16] ----------------
__global__ __launch_bounds__(256) void k_conv1(const float* __restrict__ x, const float* __restrict__ w1,
    const float* __restrict__ cb, const float* __restrict__ g, const float* __restrict__ bb,
    const float* __restrict__ m, const float* __restrict__ v, float* __restrict__ p1)
{
  __shared__ float xs[3][34][34];
  __shared__ float ws1[64*27];
  __shared__ float A1[64], B1[64];
  int b = blockIdx.x, t = threadIdx.x;
  float* xsf = &xs[0][0][0];
  for (int i = t; i < 3*34*34; i += 256) xsf[i] = 0.f;
  for (int i = t; i < 64*27; i += 256) ws1[i] = w1[i];
  if (t < 64) {
    float sc = g[t] * rsqrtf(v[t] + 1e-5f);
    A1[t] = sc;
    B1[t] = (cb[t] - m[t])*sc + bb[t];
  }
  __syncthreads();
  for (int i = t; i < 3*1024; i += 256) {
    int ci = i >> 10, rem = i & 1023, y = rem >> 5, xx = rem & 31;
    xs[ci][y+1][xx+1] = x[((size_t)b*3 + ci)*1024 + rem];
  }
  __syncthreads();
  int py = t >> 4, px = t & 15;
  int y0 = py*2, x0 = px*2;
  for (int co = 0; co < 64; ++co) {
    float a00=0.f,a01=0.f,a10=0.f,a11=0.f;
#pragma unroll
    for (int ci = 0; ci < 3; ++ci) {
      const float* xb = &xs[ci][y0][x0];
      float r0a=xb[0],r0b=xb[1],r0c=xb[2],r0d=xb[3];
      float r1a=xb[34],r1b=xb[35],r1c=xb[36],r1d=xb[37];
      float r2a=xb[68],r2b=xb[69],r2c=xb[70],r2d=xb[71];
      float r3a=xb[102],r3b=xb[103],r3c=xb[104],r3d=xb[105];
      const float* wp = &ws1[co*27 + ci*9];
      float ww0=wp[0],ww1=wp[1],ww2=wp[2],ww3=wp[3],ww4=wp[4],ww5=wp[5],ww6=wp[6],ww7=wp[7],ww8=wp[8];
      a00 += ww0*r0a+ww1*r0b+ww2*r0c + ww3*r1a+ww4*r1b+ww5*r1c + ww6*r2a+ww7*r2b+ww8*r2c;
      a01 += ww0*r0b+ww1*r0c+ww2*r0d + ww3*r1b+ww4*r1c+ww5*r1d + ww6*r2b+ww7*r2c+ww8*r2d;
      a10 += ww0*r1a+ww1*r1b+ww2*r1c + ww3*r2a+ww4*r2b+ww5*r2c + ww6*r3a+ww7*r3b+ww8*r3c;
      a11 += ww0*r1b+ww1*r1c+ww2*r1d + ww3*r2b+ww4*r2c+ww5*r2d + ww6*r3b+ww7*r3c+ww8*r3d;
    }
    float sc = A1[co], sh = B1[co];
    float vmax = fmaxf(fmaxf(a00*sc+sh, a01*sc+sh), fmaxf(a10*sc+sh, a11*sc+sh));
    vmax = fmaxf(vmax, 0.f);
    p1[(((size_t)b*64 + co)*16 + py)*16 + px] = vmax;
  }
}

// ---------------- conv2: 64->128, 16x16, BN+ReLU+maxpool2 -> [512,128,8,8] ----------------
// weights read directly from global (L2-resident); no LDS weight staging, no it-loop barriers
__global__ __launch_bounds__(256) void k_conv2(const float* __restrict__ p1, const float* __restrict__ w2,
    const float* __restrict__ cb, const float* __restrict__ g, const float* __restrict__ bb,
    const float* __restrict__ m, const float* __restrict__ v, float* __restrict__ p2)
{
  __shared__ float xs[64][18][18];
  __shared__ float A2[128], B2[128];
  int b = blockIdx.x, t = threadIdx.x;
  float* xsf = &xs[0][0][0];
  for (int i = t; i < 64*18*18; i += 256) xsf[i] = 0.f;
  if (t < 128) {
    float sc = g[t] * rsqrtf(v[t] + 1e-5f);
    A2[t] = sc;
    B2[t] = (cb[t] - m[t])*sc + bb[t];
  }
  __syncthreads();
  for (int i = t; i < 64*256; i += 256) {
    int ci = i >> 8, rem = i & 255, y = rem >> 4, xx = rem & 15;
    xs[ci][y+1][xx+1] = p1[((size_t)b*64 + ci)*256 + rem];
  }
  __syncthreads();
  int lane = t & 3, pos = t >> 2;
  int py = pos >> 3, px = pos & 7;
  int y0 = py*2, x0 = px*2;
  for (int it = 0; it < 32; ++it) {
    int co = it*4 + lane;
    const float* wco = w2 + (size_t)co*576;
    float a00=0.f,a01=0.f,a10=0.f,a11=0.f;
    for (int ci = 0; ci < 64; ++ci) {
      const float* xb = &xs[ci][y0][x0];
      float r0a=xb[0],r0b=xb[1],r0c=xb[2],r0d=xb[3];
      float r1a=xb[18],r1b=xb[19],r1c=xb[20],r1d=xb[21];
      float r2a=xb[36],r2b=xb[37],r2c=xb[38],r2d=xb[39];
      float r3a=xb[54],r3b=xb[55],r3c=xb[56],r3d=xb[57];
      const float* wp = wco + ci*9;
      float ww0=wp[0],ww1=wp[1],ww2=wp[2],ww3=wp[3],ww4=wp[4],ww5=wp[5],ww6=wp[6],ww7=wp[7],ww8=wp[8];
      a00 += ww0*r0a+ww1*r0b+ww2*r0c + ww3*r1a+ww4*r1b+ww5*r1c + ww6*r2a+ww7*r2b+ww8*r2c;
      a01 += ww0*r0b+ww1*r0c+ww2*r0d + ww3*r1b+ww4*r1c+ww5*r1d + ww6*r2b+ww7*r2c+ww8*r2d;
      a10 += ww0*r1a+ww1*r1b+ww2*r1c + ww3*r2a+ww4*r2b+ww5*r2c + ww6*r3a+ww7*r3b+ww8*r3c;
      a11 += ww0*r1b+ww1*r1c+ww2*r1d + ww3*r2b+ww4*r2c+ww5*r2d + ww6*r3b+ww7*r3c+ww8*r3d;
    }
    float sc = A2[co], sh = B2[co];
    float vmax = fmaxf(fmaxf(a00*sc+sh, a01*sc+sh), fmaxf(a10*sc+sh, a11*sc+sh));
    vmax = fmaxf(vmax, 0.f);
    p2[(((size_t)b*128 + co)*8 + py)*8 + px] = vmax;
  }
}

// ---------------- conv3: 128->256, 8x8, BN+ReLU+global-mean -> h [512,256] ----------------
// weights from global; LDS ~53 KB -> 2 blocks/CU; red2 reduce barriers kept
__global__ __launch_bounds__(256) void k_conv3(const float* __restrict__ p2, const float* __restrict__ w3,
    const float* __restrict__ cb, const float* __restrict__ g, const float* __restrict__ bb,
    const float* __restrict__ m, const float* __restrict__ v, float* __restrict__ h)
{
  __shared__ float xs[128][10][10];
  __shared__ float A3[256], B3[256];
  __shared__ float red2[256];
  int b = blockIdx.x, t = threadIdx.x;
  float* xsf = &xs[0][0][0];
  for (int i = t; i < 128*100; i += 256) xsf[i] = 0.f;
  {
    float sc = g[t] * rsqrtf(v[t] + 1e-5f);
    A3[t] = sc;
    B3[t] = (cb[t] - m[t])*sc + bb[t];
  }
  __syncthreads();
  for (int i = t; i < 128*64; i += 256) {
    int ci = i >> 6, rem = i & 63, y = rem >> 3, xx = rem & 7;
    xs[ci][y+1][xx+1] = p2[((size_t)b*128 + ci)*64 + rem];
  }
  __syncthreads();
  int lane = t & 15, cluster = t >> 4;
  int cy = cluster >> 2, cx = cluster & 3;
  int y0 = cy*2, x0 = cx*2;
  for (int it = 0; it < 16; ++it) {
    int co = it*16 + lane;
    const float* wco = w3 + (size_t)co*1152;
    float a00=0.f,a01=0.f,a10=0.f,a11=0.f;
    for (int ci = 0; ci < 128; ++ci) {
      const float* xb = &xs[ci][y0][x0];
      float r0a=xb[0],r0b=xb[1],r0c=xb[2],r0d=xb[3];
      float r1a=xb[10],r1b=xb[11],r1c=xb[12],r1d=xb[13];
      float r2a=xb[20],r2b=xb[21],r2c=xb[22],r2d=xb[23];
      float r3a=xb[30],r3b=xb[31],r3c=xb[32],r3d=xb[33];
      const float* wp = wco + ci*9;
      float ww0=wp[0],ww1=wp[1],ww2=wp[2],ww3=wp[3],ww4=wp[4],ww5=wp[5],ww6=wp[6],ww7=wp[7],ww8=wp[8];
      a00 += ww0*r0a+ww1*r0b+ww2*r0c + ww3*r1a+ww4*r1b+ww5*r1c + ww6*r2a+ww7*r2b+ww8*r2c;
      a01 += ww0*r0b+ww1*r0c+ww2*r0d + ww3*r1b+ww4*r1c+ww5*r1d + ww6*r2b+ww7*r2c+ww8*r2d;
      a10 += ww0*r1a+ww1*r1b+ww2*r1c + ww3*r2a+ww4*r2b+ww5*r2c + ww6*r3a+ww7*r3b+ww8*r3c;
      a11 += ww0*r1b+ww1*r1c+ww2*r1d + ww3*r2b+ww4*r2c+ww5*r2d + ww6*r3b+ww7*r3c+ww8*r3d;
    }
    float sc = A3[co], sh = B3[co];
    float local = fmaxf(a00*sc+sh,0.f)+fmaxf(a01*sc+sh,0.f)+fmaxf(a10*sc+sh,0.f)+fmaxf(a11*sc+sh,0.f);
    red2[cluster*16 + lane] = local;
    __syncthreads();
    if (t < 16) {
      float s2 = 0.f;
      for (int c2 = 0; c2 < 16; ++c2) s2 += red2[c2*16 + t];
      h[(size_t)b*256 + it*16 + t] = s2 * (1.f/64.f);
    }
    __syncthreads();
  }
}

// ---------------- linear + LN (+relu, +residual), f32 weights ----------------
template<int DIN, int DOUT, bool RELU, bool RESID>
__global__ __launch_bounds__(DOUT) void k_lin_ln(
    const float* __restrict__ in, const float* __restrict__ W, const float* __restrict__ bias,
    const float* __restrict__ g, const float* __restrict__ be,
    const float* __restrict__ resid, float* __restrict__ out, int ostride, int ooff)
{
  __shared__ float xs[DIN];
  __shared__ float red[DOUT];
  int b = blockIdx.x, t = threadIdx.x;
  for (int i = t; i < DIN; i += DOUT) xs[i] = in[(size_t)b*DIN + i];
  __syncthreads();
  float acc = dot_f32_row<DIN>(W + (size_t)t*DIN, xs) + bias[t];
  float mean = block_sum<DOUT>(acc, red, t) * (1.f/DOUT);
  float dv = acc - mean;
  float var = block_sum<DOUT>(dv*dv, red, t) * (1.f/DOUT);
  float y = dv * rsqrtf(var + 1e-5f) * g[t] + be[t];
  if (RELU) y = fmaxf(y, 0.f);
  if (RESID) y += resid[(size_t)b*DOUT + t];
  out[(size_t)b*ostride + ooff + t] = y;
}

// ---------------- fastslow step a: s = x@sw.T + sb ; inverse row norms ----------------
__global__ __launch_bounds__(256) void k_lin_rownorm(const float* __restrict__ in, const float* __restrict__ sw,
    const float* __restrict__ sb, float* __restrict__ sout, float* __restrict__ xninv, float* __restrict__ sninv)
{
  int b = blockIdx.x, t = threadIdx.x;
  __shared__ float xs[256];
  __shared__ float red[256];
  xs[t] = in[(size_t)b*256 + t];
  __syncthreads();
  float acc = dot_f32_row<256>(sw + (size_t)t*256, xs) + sb[t];
  sout[(size_t)b*256 + t] = acc;
  float xn2 = block_sum<256>(xs[t]*xs[t], red, t);
  float sn2 = block_sum<256>(acc*acc, red, t);
  if (t == 0) {
    xninv[b] = 1.f / fmaxf(sqrtf(xn2), 1e-12f);
    sninv[b] = 1.f / fmaxf(sqrtf(sn2), 1e-12f);
  }
}

// ---------------- fastslow step b: hebbian update -> effective weights/bias ----------------
__global__ __launch_bounds__(256) void k_hebb(const float* __restrict__ x, const float* __restrict__ s,
    const float* __restrict__ xninv, const float* __restrict__ sninv,
    const float* __restrict__ sw, const float* __restrict__ fw,
    const float* __restrict__ sb, const float* __restrict__ fb,
    float lr, float decay, float* __restrict__ weff, float* __restrict__ beff)
{
  int o = blockIdx.x, t = threadIdx.x;
  __shared__ float c[512];
  __shared__ float sonb[512];
  __shared__ float red[256];
  for (int b = t; b < 512; b += 256) {
    float son = s[(size_t)b*256 + o] * sninv[b];
    sonb[b] = son;
    c[b] = son * xninv[b];
  }
  __syncthreads();
  float acc = 0.f;
  for (int b = 0; b < 512; ++b) acc += c[b] * x[(size_t)b*256 + t];
  float hebb = acc * (1.f/512.f);
  float fwn = fw[(size_t)o*256 + t] * decay + lr * hebb;
  float wn2 = block_sum<256>(fwn*fwn, red, t);
  float wn = sqrtf(wn2);
  float scale = (wn > 0.25f) ? 0.25f/(wn + 1e-8f) : 1.f;
  weff[(size_t)o*256 + t] = sw[(size_t)o*256 + t] + fwn*scale;
  float sm = block_sum<256>(sonb[t] + sonb[t+256], red, t) * (1.f/512.f);
  if (t == 0) {
    float fbe = fb[o] * decay + lr * sm;
    fbe = fminf(fmaxf(fbe, -0.2f), 0.2f);
    beff[o] = sb[o] + fbe;
  }
}

// ---------------- column partials: per-block 8 rows, coalesced ----------------
__global__ __launch_bounds__(256) void k_colpart(const float* __restrict__ src,
    float* __restrict__ psum, float* __restrict__ psumsq)
{
  int j = blockIdx.x, t = threadIdx.x;
  float s1 = 0.f, s2 = 0.f;
#pragma unroll
  for (int r = 0; r < 8; ++r) {
    float val = src[((size_t)j*8 + r)*256 + t];
    s1 += val;
    s2 += val*val;
  }
  psum[t*64 + j] = s1;
  psumsq[t*64 + j] = s2;
}

// ---------------- memnew = 0.9*mem + 0.1*colmean(hc) ----------------
__global__ __launch_bounds__(256) void k_mem_fin(const float* __restrict__ psum, const float* __restrict__ mem,
                                                 float* __restrict__ memnew)
{
  int t = threadIdx.x;
  float s = 0.f;
  const float* p = psum + t*64;
#pragma unroll 8
  for (int j = 0; j < 64; ++j) s += p[j];
  memnew[t] = 0.9f*mem[t] + 0.1f*(s * (1.f/512.f));
}

__global__ __launch_bounds__(256) void k_x2(const float* __restrict__ hc, const float* __restrict__ memnew,
                                            float* __restrict__ x2)
{
  int i = blockIdx.x*256 + threadIdx.x;
  x2[i] = hc[i] + 0.3f*memnew[i & 255];
}

// ---------------- column stats finalize (am, ainv with ddof=1) ----------------
__global__ __launch_bounds__(256) void k_colstats_fin(const float* __restrict__ psum, const float* __restrict__ psumsq,
                                                       float* __restrict__ am, float* __restrict__ ainv)
{
  int t = threadIdx.x;
  float s1 = 0.f, s2 = 0.f;
  const float* p1 = psum + t*64;
  const float* p2 = psumsq + t*64;
#pragma unroll 8
  for (int j = 0; j < 64; ++j) { s1 += p1[j]; s2 += p2[j]; }
  float mean = s1 * (1.f/512.f);
  float var = fmaxf((s2 - 512.f*mean*mean) * (1.f/511.f), 0.f);
  am[t] = mean;
  ainv[t] = 1.f/(sqrtf(var) + 1e-6f);
}

// ---------------- covariance of standardized features ----------------
__global__ __launch_bounds__(256) void k_cov(const float* __restrict__ hd, const float* __restrict__ am,
    const float* __restrict__ ainv, float* __restrict__ cov)
{
  int i = blockIdx.x, t = threadIdx.x;
  __shared__ float ci[512];
  float ami = am[i], aii = ainv[i];
  for (int b = t; b < 512; b += 256) ci[b] = (hd[(size_t)b*256 + i] - ami)*aii;
  __syncthreads();
  float amj = am[t], aij = ainv[t];
  float acc = 0.f;
  for (int b = 0; b < 512; ++b) acc += ci[b] * (hd[(size_t)b*256 + t] - amj);
  float cval = acc * aij * (1.f/511.f) + ((i == t) ? 1e-4f : 0.f);
  cov[(size_t)i*256 + t] = cval;
}

// ---------------- Householder tridiagonalization — LDS triangle, row-streaming, 16 waves ----------------
// (round-8 measured-best version: wave-uniform segment branches, statically unrolled)
__global__ __launch_bounds__(1024) void k_tridiag(const float* __restrict__ A, float* __restrict__ d, float* __restrict__ e)
{
  const int n = 256;
  __shared__ float tri[32896];
  __shared__ float v[256], q[256];
  __shared__ float ppw[16][257];     // padded: kills stride-256 read conflicts
  __shared__ float redA[4], red4[4];
  __shared__ float sH;
  int t = threadIdx.x;
  int wid = t >> 6, lane = t & 63;

  // load lower triangle from global cov
  for (int i = t; i < 32896; i += 1024) {
    int r = (int)((sqrtf(8.f*(float)i + 1.f) - 1.f) * 0.5f);
    while ((r+1)*(r+2)/2 <= i) ++r;
    while (r*(r+1)/2 > i) --r;
    int c = i - r*(r+1)/2;
    tri[i] = A[(size_t)r*n + c];
  }
  __syncthreads();

  for (int k = 0; k < n-2; ++k) {
    int m = n-1-k;
    int base = k+1;

    // Phase A: gather column k -> v, reduce sigma
    float xi = 0.f;
    if (t < m) {
      int R = base + t;
      xi = tri[R*(R+1)/2 + k];
      v[t] = xi;
    }
    if (t < 256) {
      float val = xi*xi;
#pragma unroll
      for (int mk = 1; mk < 64; mk <<= 1) val += __shfl_xor(val, mk, 64);
      if (lane == 0) redA[wid] = val;
    }
    __syncthreads();                   // B1
    if (t == 0) {
      float sigma = redA[0]+redA[1]+redA[2]+redA[3];
      float x0 = v[0];
      float alpha = (x0 >= 0.f) ? -sqrtf(sigma) : sqrtf(sigma);
      sH = sigma - x0*alpha;
      e[k] = alpha;
      v[0] = x0 - alpha;
    }
    __syncthreads();                   // B2
    float H = sH;
    if (H <= 1e-32f) continue;         // uniform (sH shared)

    // Phase B: row-streaming matvec; per-lane register p-partials (slot c owns index 64c+lane)
    float p0=0.f, p1=0.f, p2=0.f, p3=0.f;
    for (int r = wid; r < m; r += 16) {
      int R = base + r;
      int rowoff = R*(R+1)/2 + base;
      float vr = v[r];
      float dot = 0.f;
#pragma unroll
      for (int c = 0; c < 4; ++c) {
        if (64*c <= r) {
          int j = 64*c + lane;
          float val = (j <= r) ? tri[rowoff + j] : 0.f;
          dot += val * v[j];
          float sval = (j < r) ? val : 0.f;   // diagonal excluded from scatter
          float contrib = sval * vr;
          if (c == 0) p0 += contrib; else if (c == 1) p1 += contrib;
          else if (c == 2) p2 += contrib; else p3 += contrib;
        }
      }
#pragma unroll
      for (int mk = 1; mk < 64; mk <<= 1) dot += __shfl_xor(dot, mk, 64);
      if (lane == (r & 63)) {          // owner lane of p[r] in this wave
        int sl = r >> 6;
        if (sl == 0) p0 += dot; else if (sl == 1) p1 += dot;
        else if (sl == 2) p2 += dot; else p3 += dot;
      }
    }
    ppw[wid][lane]      = p0;
    ppw[wid][64+lane]   = p1;
    ppw[wid][128+lane]  = p2;
    ppw[wid][192+lane]  = p3;
    __syncthreads();                   // B3

    // Phase C: cross-wave p reduce, Kv reduce, q
    float pt = 0.f;
    if (t < 256) {
      float kv = 0.f;
#pragma unroll
      for (int w2 = 0; w2 < 16; ++w2) pt += ppw[w2][t];
      pt /= H;
      if (t < m) kv = v[t] * pt;
#pragma unroll
      for (int mk = 1; mk < 64; mk <<= 1) kv += __shfl_xor(kv, mk, 64);
      if (lane == 0) red4[wid] = kv;
    }
    __syncthreads();                   // B4
    if (t < m) {
      float Kv = (red4[0]+red4[1]+red4[2]+red4[3]) / (2.f*H);
      q[t] = pt - Kv*v[t];
    }
    __syncthreads();                   // B5

    // Phase D: row-streaming rank-2 update (conflict-free consecutive rmw)
    for (int r = wid; r < m; r += 16) {
      int R = base + r;
      int rowoff = R*(R+1)/2 + base;
      float vr = v[r], qr = q[r];
#pragma unroll
      for (int c = 0; c < 4; ++c) {
        if (64*c <= r) {
          int j = 64*c + lane;
          if (j <= r) tri[rowoff + j] -= vr*q[j] + qr*v[j];
        }
      }
    }
    __syncthreads();                   // B6
  }
  if (t == 0) {
    e[n-2] = tri[((n-1)*n)/2 + (n-2)];
    e[n-1] = 0.f;
  }
  if (t < n) d[t] = tri[(t*(t+1))/2 + t];
}

// ---------------- bisection eigenvalues + entropy -> coef ----------------
__global__ __launch_bounds__(256) void k_eig_coef(const float* __restrict__ dg, const float* __restrict__ eg,
                                                  float* __restrict__ coefout)
{
  const int n = 256;
  int t = threadIdx.x;
  __shared__ float sd[256], se2[256], sea[256], red[256];
  sd[t] = dg[t];
  float ev = (t < n-1) ? eg[t] : 0.f;
  se2[t] = ev*ev;
  sea[t] = fabsf(ev);
  __syncthreads();
  float r = ((t > 0) ? sea[t-1] : 0.f) + sea[t];
  red[t] = sd[t] - r; __syncthreads();
  for (int s = 128; s > 0; s >>= 1) { if (t < s) red[t] = fminf(red[t], red[t+s]); __syncthreads(); }
  float glo = red[0] - 1e-3f; __syncthreads();
  red[t] = sd[t] + r; __syncthreads();
  for (int s = 128; s > 0; s >>= 1) { if (t < s) red[t] = fmaxf(red[t], red[t+s]); __syncthreads(); }
  float ghi = red[0] + 1e-3f; __syncthreads();

  float lo = glo, hi = ghi;
  for (int it = 0; it < 28; ++it) {
    float mid = 0.5f*(lo + hi);
    int cnt = 0;
    float qq = sd[0] - mid;
    cnt += (qq < 0.f);
    for (int i = 1; i < n; ++i) {
      float denom = qq;
      if (fabsf(denom) < 1e-20f) denom = (denom < 0.f) ? -1e-20f : 1e-20f;
      qq = sd[i] - mid - se2[i-1]/denom;
      cnt += (qq < 0.f);
    }
    if (cnt <= t) lo = mid; else hi = mid;
  }
  float lam = fmaxf(0.5f*(lo + hi), 0.f);
  float tot = block_sum<256>(lam, red, t) + 1e-8f;
  float en = lam / tot;
  float contrib = -en * logf(en + 1e-8f);
  float ent = block_sum<256>(contrib, red, t);
  if (t == 0) {
    float phi = ent / logf(256.f);
    float phi_eff = fminf(fmaxf(0.3f*phi, 0.f), 1.f);
    float strength = 1.f/(1.f + expf(-(phi_eff - 0.1f)*5.f));
    coefout[0] = (phi_eff > 0.1f) ? strength : 0.1f;
  }
}

// ---------------- fused consciousness net: t1 = relu(LN(hd@W1+b1)); hcon = hd + coef*(t1@W2+b2) ----------------
__global__ __launch_bounds__(256) void k_cn(const float* __restrict__ hd, const float* __restrict__ W1,
    const float* __restrict__ b1, const float* __restrict__ g, const float* __restrict__ be,
    const float* __restrict__ W2, const float* __restrict__ b2, const float* __restrict__ coefp,
    float* __restrict__ hcon)
{
  __shared__ float xs[256];
  __shared__ float t1s[256];
  __shared__ float red[256];
  int b = blockIdx.x, t = threadIdx.x;
  xs[t] = hd[(size_t)b*256 + t];
  __syncthreads();
  float acc = dot_f32_row<256>(W1 + (size_t)t*256, xs) + b1[t];
  float mean = block_sum<256>(acc, red, t) * (1.f/256.f);
  float dv = acc - mean;
  float var = block_sum<256>(dv*dv, red, t) * (1.f/256.f);
  t1s[t] = fmaxf(dv * rsqrtf(var + 1e-5f) * g[t] + be[t], 0.f);
  __syncthreads();
  float acc2 = dot_f32_row<256>(W2 + (size_t)t*256, t1s) + b2[t];
  hcon[(size_t)b*256 + t] = xs[t] + coefp[0]*acc2;
}

// ---------------- fused projection + classifier ----------------
__global__ __launch_bounds__(128) void k_pr_cls(const float* __restrict__ hcon, const float* __restrict__ W,
    const float* __restrict__ bias, const float* __restrict__ g, const float* __restrict__ be,
    const float* __restrict__ Wc, const float* __restrict__ bc, float* __restrict__ out)
{
  __shared__ float xs[256];
  __shared__ float hp[128];
  __shared__ float red[128];
  int b = blockIdx.x, t = threadIdx.x;
  xs[t] = hcon[(size_t)b*256 + t];
  xs[t+128] = hcon[(size_t)b*256 + t + 128];
  __syncthreads();
  float acc = dot_f32_row<256>(W + (size_t)t*256, xs) + bias[t];
  float mean = block_sum<128>(acc, red, t) * (1.f/128.f);
  float dv = acc - mean;
  float var = block_sum<128>(dv*dv, red, t) * (1.f/128.f);
  hp[t] = fmaxf(dv * rsqrtf(var + 1e-5f) * g[t] + be[t], 0.f);
  __syncthreads();
  if (t < 10) {
    float a2 = bc[t];
    const float* wr = Wc + (size_t)t*128;
    for (int i = 0; i < 128; ++i) a2 += wr[i]*hp[i];
    out[(size_t)b*10 + t] = a2;
  }
}

// ================= host launcher =================
extern "C" void kernel_launch(void* const* d_in, const int* in_sizes, int n_in,
                              void* d_out, int out_size, void* d_ws, size_t ws_size,
                              hipStream_t stream)
{
  (void)in_sizes; (void)n_in; (void)out_size; (void)ws_size;
  const float* x     = (const float*)d_in[0];
  const float* c1w   = (const float*)d_in[1];
  const float* c1b   = (const float*)d_in[2];
  const float* bn1g  = (const float*)d_in[3];
  const float* bn1b  = (const float*)d_in[4];
  const float* bn1m  = (const float*)d_in[5];
  const float* bn1v  = (const float*)d_in[6];
  const float* c2w   = (const float*)d_in[7];
  const float* c2b   = (const float*)d_in[8];
  const float* bn2g  = (const float*)d_in[9];
  const float* bn2b  = (const float*)d_in[10];
  const float* bn2m  = (const float*)d_in[11];
  const float* bn2v  = (const float*)d_in[12];
  const float* c3w   = (const float*)d_in[13];
  const float* c3b   = (const float*)d_in[14];
  const float* bn3g  = (const float*)d_in[15];
  const float* bn3b  = (const float*)d_in[16];
  const float* bn3m  = (const float*)d_in[17];
  const float* bn3v  = (const float*)d_in[18];
  const float* corew = (const float*)d_in[19];
  const float* coreb = (const float*)d_in[20];
  const float* corelng = (const float*)d_in[21];
  const float* corelnb = (const float*)d_in[22];
  const float* fpsw  = (const float*)d_in[23];
  const float* fpsb  = (const float*)d_in[24];
  const float* fpfw  = (const float*)d_in[25];
  const float* fpfb  = (const float*)d_in[26];
  const float* fplng = (const float*)d_in[27];
  const float* fplnb = (const float*)d_in[28];
  const float* spsw  = (const float*)d_in[29];
  const float* spsb  = (const float*)d_in[30];
  const float* spfw  = (const float*)d_in[31];
  const float* spfb  = (const float*)d_in[32];
  const float* splng = (const float*)d_in[33];
  const float* splnb = (const float*)d_in[34];
  const float* intw  = (const float*)d_in[35];
  const float* intb  = (const float*)d_in[36];
  const float* intlng= (const float*)d_in[37];
  const float* intlnb= (const float*)d_in[38];
  const float* memi  = (const float*)d_in[39];
  const float* cnw1  = (const float*)d_in[40];
  const float* cnb1  = (const float*)d_in[41];
  const float* cnlng = (const float*)d_in[42];
  const float* cnlnb = (const float*)d_in[43];
  const float* cnw2  = (const float*)d_in[44];
  const float* cnb2  = (const float*)d_in[45];
  const float* prw   = (const float*)d_in[46];
  const float* prb   = (const float*)d_in[47];
  const float* prlng = (const float*)d_in[48];
  const float* prlnb = (const float*)d_in[49];
  const float* clw   = (const float*)d_in[50];
  const float* clb   = (const float*)d_in[51];
  float* out = (float*)d_out;

  float* w = (float*)d_ws;
  size_t off = 0;
  auto alloc = [&](size_t nel) { float* p = w + off; off += nel; return p; };
  float* p1     = alloc((size_t)512*64*16*16);
  float* p2     = alloc((size_t)512*128*8*8);
  float* h      = alloc(512*256);
  float* hc     = alloc(512*256);
  float* x2     = alloc(512*256);
  float* s      = alloc(512*256);
  float* xninv  = alloc(512);
  float* sninv  = alloc(512);
  float* memnew = alloc(256);
  float* weff   = alloc(256*256);
  float* beff   = alloc(256);
  float* comb   = alloc((size_t)512*512);
  float* hd     = alloc(512*256);
  float* am     = alloc(256);
  float* ainv   = alloc(256);
  float* cov    = alloc(256*256);
  float* dvec   = alloc(256);
  float* evec   = alloc(256);
  float* coefb  = alloc(8);
  float* hcon   = alloc(512*256);
  float* psum   = alloc(256*64);
  float* psumsq = alloc(256*64);

  // encoder
  k_conv1<<<512,256,0,stream>>>(x, c1w, c1b, bn1g, bn1b, bn1m, bn1v, p1);
  k_conv2<<<512,256,0,stream>>>(p1, c2w, c2b, bn2g, bn2b, bn2m, bn2v, p2);
  k_conv3<<<512,256,0,stream>>>(p2, c3w, c3b, bn3g, bn3b, bn3m, bn3v, h);
  // core
  k_lin_ln<256,256,true,false><<<512,256,0,stream>>>(h, corew, coreb, corelng, corelnb, nullptr, hc, 256, 0);
  // memory EMA (parallel column mean) + slow-path input
  k_colpart<<<64,256,0,stream>>>(hc, psum, psumsq);
  k_mem_fin<<<1,256,0,stream>>>(psum, memi, memnew);
  k_x2<<<512,256,0,stream>>>(hc, memnew, x2);
  // fast path (lr=0.015, decay=0.95)
  k_lin_rownorm<<<512,256,0,stream>>>(hc, fpsw, fpsb, s, xninv, sninv);
  k_hebb<<<256,256,0,stream>>>(hc, s, xninv, sninv, fpsw, fpfw, fpsb, fpfb, 0.015f, 0.95f, weff, beff);
  k_lin_ln<256,256,false,false><<<512,256,0,stream>>>(hc, weff, beff, fplng, fplnb, nullptr, comb, 512, 0);
  // slow path (lr=0.005, decay=0.97)
  k_lin_rownorm<<<512,256,0,stream>>>(x2, spsw, spsb, s, xninv, sninv);
  k_hebb<<<256,256,0,stream>>>(x2, s, xninv, sninv, spsw, spfw, spsb, spfb, 0.005f, 0.97f, weff, beff);
  k_lin_ln<256,256,false,false><<<512,256,0,stream>>>(x2, weff, beff, splng, splnb, nullptr, comb, 512, 256);
  // integrator + residual
  k_lin_ln<512,256,false,true><<<512,256,0,stream>>>(comb, intw, intb, intlng, intlnb, hc, hd, 256, 0);
  // consciousness stats (parallel)
  k_colpart<<<64,256,0,stream>>>(hd, psum, psumsq);
  k_colstats_fin<<<1,256,0,stream>>>(psum, psumsq, am, ainv);
  k_cov<<<256,256,0,stream>>>(hd, am, ainv, cov);
  k_tridiag<<<1,1024,0,stream>>>(cov, dvec, evec);
  k_eig_coef<<<1,256,0,stream>>>(dvec, evec, coefb);
  // consciousness net + gated residual (fused)
  k_cn<<<512,256,0,stream>>>(hd, cnw1, cnb1, cnlng, cnlnb, cnw2, cnb2, coefb, hcon);
  // projection + classifier (fused)
  k_pr_cls<<<512,128,0,stream>>>(hcon, prw, prb, prlng, prlnb, clw, clb, out);
}

// Round 13
// 4006.924 us; speedup vs baseline: 1.1543x; 1.1543x over previous
//
#include <hip/hip_runtime.h>
#include <hip/hip_bf16.h>

// ---------------- block reduction ----------------
template<int NT>
__device__ __forceinline__ float block_sum(float v, float* red, int t) {
  red[t] = v; __syncthreads();
#pragma unroll
  for (int s = NT/2; s > 0; s >>= 1) {
    if (t < s) red[t] += red[t+s];
    __syncthreads();
  }
  float r = red[0];
  __syncthreads();
  return r;
}

// dot of an f32 row (length DIN, mult of 4) against f32 shared vector
template<int DIN>
__device__ __forceinline__ float dot_f32_row(const float* __restrict__ wr, const float* __restrict__ xs) {
  float acc = 0.f;
  const float4* wp = reinterpret_cast<const float4*>(wr);
#pragma unroll 4
  for (int i = 0; i < DIN/4; ++i) {
    float4 w4 = wp[i];
    acc += w4.x*xs[i*4] + w4.y*xs[i*4+1] + w4.z*xs[i*4+2] + w4.w*xs[i*4+3];
  }
  return acc;
}

// ---------------- conv1: 3->64, 32x32, BN+ReLU+maxpool2 -> [512,64,16,16] ----------------
__global__ __launch_bounds__(256) void k_conv1(const float* __restrict__ x, const float* __restrict__ w1,
    const float* __restrict__ cb, const float* __restrict__ g, const float* __restrict__ bb,
    const float* __restrict__ m, const float* __restrict__ v, float* __restrict__ p1)
{
  __shared__ float xs[3][34][34];
  __shared__ float ws1[64*27];
  __shared__ float A1[64], B1[64];
  int b = blockIdx.x, t = threadIdx.x;
  float* xsf = &xs[0][0][0];
  for (int i = t; i < 3*34*34; i += 256) xsf[i] = 0.f;
  for (int i = t; i < 64*27; i += 256) ws1[i] = w1[i];
  if (t < 64) {
    float sc = g[t] * rsqrtf(v[t] + 1e-5f);
    A1[t] = sc;
    B1[t] = (cb[t] - m[t])*sc + bb[t];
  }
  __syncthreads();
  for (int i = t; i < 3*1024; i += 256) {
    int ci = i >> 10, rem = i & 1023, y = rem >> 5, xx = rem & 31;
    xs[ci][y+1][xx+1] = x[((size_t)b*3 + ci)*1024 + rem];
  }
  __syncthreads();
  int py = t >> 4, px = t & 15;
  int y0 = py*2, x0 = px*2;
  for (int co = 0; co < 64; ++co) {
    float a00=0.f,a01=0.f,a10=0.f,a11=0.f;
#pragma unroll
    for (int ci = 0; ci < 3; ++ci) {
      const float* xb = &xs[ci][y0][x0];
      float r0a=xb[0],r0b=xb[1],r0c=xb[2],r0d=xb[3];
      float r1a=xb[34],r1b=xb[35],r1c=xb[36],r1d=xb[37];
      float r2a=xb[68],r2b=xb[69],r2c=xb[70],r2d=xb[71];
      float r3a=xb[102],r3b=xb[103],r3c=xb[104],r3d=xb[105];
      const float* wp = &ws1[co*27 + ci*9];
      float ww0=wp[0],ww1=wp[1],ww2=wp[2],ww3=wp[3],ww4=wp[4],ww5=wp[5],ww6=wp[6],ww7=wp[7],ww8=wp[8];
      a00 += ww0*r0a+ww1*r0b+ww2*r0c + ww3*r1a+ww4*r1b+ww5*r1c + ww6*r2a+ww7*r2b+ww8*r2c;
      a01 += ww0*r0b+ww1*r0c+ww2*r0d + ww3*r1b+ww4*r1c+ww5*r1d + ww6*r2b+ww7*r2c+ww8*r2d;
      a10 += ww0*r1a+ww1*r1b+ww2*r1c + ww3*r2a+ww4*r2b+ww5*r2c + ww6*r3a+ww7*r3b+ww8*r3c;
      a11 += ww0*r1b+ww1*r1c+ww2*r1d + ww3*r2b+ww4*r2c+ww5*r2d + ww6*r3b+ww7*r3c+ww8*r3d;
    }
    float sc = A1[co], sh = B1[co];
    float vmax = fmaxf(fmaxf(a00*sc+sh, a01*sc+sh), fmaxf(a10*sc+sh, a11*sc+sh));
    vmax = fmaxf(vmax, 0.f);
    p1[(((size_t)b*64 + co)*16 + py)*16 + px] = vmax;
  }
}

// ---------------- conv2: 64->128, 16x16, BN+ReLU+maxpool2 -> [512,128,8,8] ----------------
// weight chunk LDS layout transposed+padded: wchT[rem*5 + co_local], rem = ci*9+k
__global__ __launch_bounds__(256) void k_conv2(const float* __restrict__ p1, const float* __restrict__ w2,
    const float* __restrict__ cb, const float* __restrict__ g, const float* __restrict__ bb,
    const float* __restrict__ m, const float* __restrict__ v, float* __restrict__ p2)
{
  __shared__ float xs[64][18][18];
  __shared__ float wchT[576*5];
  __shared__ float A2[128], B2[128];
  int b = blockIdx.x, t = threadIdx.x;
  float* xsf = &xs[0][0][0];
  for (int i = t; i < 64*18*18; i += 256) xsf[i] = 0.f;
  if (t < 128) {
    float sc = g[t] * rsqrtf(v[t] + 1e-5f);
    A2[t] = sc;
    B2[t] = (cb[t] - m[t])*sc + bb[t];
  }
  __syncthreads();
  for (int i = t; i < 64*256; i += 256) {
    int ci = i >> 8, rem = i & 255, y = rem >> 4, xx = rem & 15;
    xs[ci][y+1][xx+1] = p1[((size_t)b*64 + ci)*256 + rem];
  }
  int lane = t & 3, pos = t >> 2;
  int py = pos >> 3, px = pos & 7;
  int y0 = py*2, x0 = px*2;
  for (int it = 0; it < 32; ++it) {
    __syncthreads();
    for (int i = t; i < 2304; i += 256) {
      int rem = i % 576, co = i / 576;
      wchT[rem*5 + co] = w2[(size_t)it*2304 + i];
    }
    __syncthreads();
    float a00=0.f,a01=0.f,a10=0.f,a11=0.f;
    for (int ci = 0; ci < 64; ++ci) {
      const float* xb = &xs[ci][y0][x0];
      float r0a=xb[0],r0b=xb[1],r0c=xb[2],r0d=xb[3];
      float r1a=xb[18],r1b=xb[19],r1c=xb[20],r1d=xb[21];
      float r2a=xb[36],r2b=xb[37],r2c=xb[38],r2d=xb[39];
      float r3a=xb[54],r3b=xb[55],r3c=xb[56],r3d=xb[57];
      const float* wp = &wchT[(ci*9)*5 + lane];
      float ww0=wp[0],ww1=wp[5],ww2=wp[10],ww3=wp[15],ww4=wp[20],ww5=wp[25],ww6=wp[30],ww7=wp[35],ww8=wp[40];
      a00 += ww0*r0a+ww1*r0b+ww2*r0c + ww3*r1a+ww4*r1b+ww5*r1c + ww6*r2a+ww7*r2b+ww8*r2c;
      a01 += ww0*r0b+ww1*r0c+ww2*r0d + ww3*r1b+ww4*r1c+ww5*r1d + ww6*r2b+ww7*r2c+ww8*r2d;
      a10 += ww0*r1a+ww1*r1b+ww2*r1c + ww3*r2a+ww4*r2b+ww5*r2c + ww6*r3a+ww7*r3b+ww8*r3c;
      a11 += ww0*r1b+ww1*r1c+ww2*r1d + ww3*r2b+ww4*r2c+ww5*r2d + ww6*r3b+ww7*r3c+ww8*r3d;
    }
    int co = it*4 + lane;
    float sc = A2[co], sh = B2[co];
    float vmax = fmaxf(fmaxf(a00*sc+sh, a01*sc+sh), fmaxf(a10*sc+sh, a11*sc+sh));
    vmax = fmaxf(vmax, 0.f);
    p2[(((size_t)b*128 + co)*8 + py)*8 + px] = vmax;
  }
}

// ---------------- conv3: 128->256, 8x8, BN+ReLU+global-mean -> h [512,256] ----------------
// weight chunk LDS layout transposed+padded: wchT[rem*17 + co_local], rem = ci*9+k
__global__ __launch_bounds__(256) void k_conv3(const float* __restrict__ p2, const float* __restrict__ w3,
    const float* __restrict__ cb, const float* __restrict__ g, const float* __restrict__ bb,
    const float* __restrict__ m, const float* __restrict__ v, float* __restrict__ h)
{
  __shared__ float xs[128][10][10];
  __shared__ float wchT[1152*17];
  __shared__ float A3[256], B3[256];
  __shared__ float red2[256];
  int b = blockIdx.x, t = threadIdx.x;
  float* xsf = &xs[0][0][0];
  for (int i = t; i < 128*100; i += 256) xsf[i] = 0.f;
  {
    float sc = g[t] * rsqrtf(v[t] + 1e-5f);
    A3[t] = sc;
    B3[t] = (cb[t] - m[t])*sc + bb[t];
  }
  __syncthreads();
  for (int i = t; i < 128*64; i += 256) {
    int ci = i >> 6, rem = i & 63, y = rem >> 3, xx = rem & 7;
    xs[ci][y+1][xx+1] = p2[((size_t)b*128 + ci)*64 + rem];
  }
  int lane = t & 15, cluster = t >> 4;
  int cy = cluster >> 2, cx = cluster & 3;
  int y0 = cy*2, x0 = cx*2;
  for (int it = 0; it < 16; ++it) {
    __syncthreads();
    for (int i = t; i < 18432; i += 256) {
      int rem = i % 1152, co = i / 1152;
      wchT[rem*17 + co] = w3[(size_t)it*18432 + i];
    }
    __syncthreads();
    float a00=0.f,a01=0.f,a10=0.f,a11=0.f;
    for (int ci = 0; ci < 128; ++ci) {
      const float* xb = &xs[ci][y0][x0];
      float r0a=xb[0],r0b=xb[1],r0c=xb[2],r0d=xb[3];
      float r1a=xb[10],r1b=xb[11],r1c=xb[12],r1d=xb[13];
      float r2a=xb[20],r2b=xb[21],r2c=xb[22],r2d=xb[23];
      float r3a=xb[30],r3b=xb[31],r3c=xb[32],r3d=xb[33];
      const float* wp = &wchT[(ci*9)*17 + lane];
      float ww0=wp[0],ww1=wp[17],ww2=wp[34],ww3=wp[51],ww4=wp[68],ww5=wp[85],ww6=wp[102],ww7=wp[119],ww8=wp[136];
      a00 += ww0*r0a+ww1*r0b+ww2*r0c + ww3*r1a+ww4*r1b+ww5*r1c + ww6*r2a+ww7*r2b+ww8*r2c;
      a01 += ww0*r0b+ww1*r0c+ww2*r0d + ww3*r1b+ww4*r1c+ww5*r1d + ww6*r2b+ww7*r2c+ww8*r2d;
      a10 += ww0*r1a+ww1*r1b+ww2*r1c + ww3*r2a+ww4*r2b+ww5*r2c + ww6*r3a+ww7*r3b+ww8*r3c;
      a11 += ww0*r1b+ww1*r1c+ww2*r1d + ww3*r2b+ww4*r2c+ww5*r2d + ww6*r3b+ww7*r3c+ww8*r3d;
    }
    int co = it*16 + lane;
    float sc = A3[co], sh = B3[co];
    float local = fmaxf(a00*sc+sh,0.f)+fmaxf(a01*sc+sh,0.f)+fmaxf(a10*sc+sh,0.f)+fmaxf(a11*sc+sh,0.f);
    red2[cluster*16 + lane] = local;
    __syncthreads();
    if (t < 16) {
      float s2 = 0.f;
      for (int c2 = 0; c2 < 16; ++c2) s2 += red2[c2*16 + t];
      h[(size_t)b*256 + it*16 + t] = s2 * (1.f/64.f);
    }
  }
}

// ---------------- linear + LN (+relu, +residual), f32 weights ----------------
template<int DIN, int DOUT, bool RELU, bool RESID>
__global__ __launch_bounds__(DOUT) void k_lin_ln(
    const float* __restrict__ in, const float* __restrict__ W, const float* __restrict__ bias,
    const float* __restrict__ g, const float* __restrict__ be,
    const float* __restrict__ resid, float* __restrict__ out, int ostride, int ooff)
{
  __shared__ float xs[DIN];
  __shared__ float red[DOUT];
  int b = blockIdx.x, t = threadIdx.x;
  for (int i = t; i < DIN; i += DOUT) xs[i] = in[(size_t)b*DIN + i];
  __syncthreads();
  float acc = dot_f32_row<DIN>(W + (size_t)t*DIN, xs) + bias[t];
  float mean = block_sum<DOUT>(acc, red, t) * (1.f/DOUT);
  float dv = acc - mean;
  float var = block_sum<DOUT>(dv*dv, red, t) * (1.f/DOUT);
  float y = dv * rsqrtf(var + 1e-5f) * g[t] + be[t];
  if (RELU) y = fmaxf(y, 0.f);
  if (RESID) y += resid[(size_t)b*DOUT + t];
  out[(size_t)b*ostride + ooff + t] = y;
}

// ---------------- fastslow step a: s = x@sw.T + sb ; inverse row norms ----------------
__global__ __launch_bounds__(256) void k_lin_rownorm(const float* __restrict__ in, const float* __restrict__ sw,
    const float* __restrict__ sb, float* __restrict__ sout, float* __restrict__ xninv, float* __restrict__ sninv)
{
  int b = blockIdx.x, t = threadIdx.x;
  __shared__ float xs[256];
  __shared__ float red[256];
  xs[t] = in[(size_t)b*256 + t];
  __syncthreads();
  float acc = dot_f32_row<256>(sw + (size_t)t*256, xs) + sb[t];
  sout[(size_t)b*256 + t] = acc;
  float xn2 = block_sum<256>(xs[t]*xs[t], red, t);
  float sn2 = block_sum<256>(acc*acc, red, t);
  if (t == 0) {
    xninv[b] = 1.f / fmaxf(sqrtf(xn2), 1e-12f);
    sninv[b] = 1.f / fmaxf(sqrtf(sn2), 1e-12f);
  }
}

// ---------------- fastslow step b: hebbian update -> effective weights/bias ----------------
__global__ __launch_bounds__(256) void k_hebb(const float* __restrict__ x, const float* __restrict__ s,
    const float* __restrict__ xninv, const float* __restrict__ sninv,
    const float* __restrict__ sw, const float* __restrict__ fw,
    const float* __restrict__ sb, const float* __restrict__ fb,
    float lr, float decay, float* __restrict__ weff, float* __restrict__ beff)
{
  int o = blockIdx.x, t = threadIdx.x;
  __shared__ float c[512];
  __shared__ float sonb[512];
  __shared__ float red[256];
  for (int b = t; b < 512; b += 256) {
    float son = s[(size_t)b*256 + o] * sninv[b];
    sonb[b] = son;
    c[b] = son * xninv[b];
  }
  __syncthreads();
  float acc = 0.f;
  for (int b = 0; b < 512; ++b) acc += c[b] * x[(size_t)b*256 + t];
  float hebb = acc * (1.f/512.f);
  float fwn = fw[(size_t)o*256 + t] * decay + lr * hebb;
  float wn2 = block_sum<256>(fwn*fwn, red, t);
  float wn = sqrtf(wn2);
  float scale = (wn > 0.25f) ? 0.25f/(wn + 1e-8f) : 1.f;
  weff[(size_t)o*256 + t] = sw[(size_t)o*256 + t] + fwn*scale;
  float sm = block_sum<256>(sonb[t] + sonb[t+256], red, t) * (1.f/512.f);
  if (t == 0) {
    float fbe = fb[o] * decay + lr * sm;
    fbe = fminf(fmaxf(fbe, -0.2f), 0.2f);
    beff[o] = sb[o] + fbe;
  }
}

// ---------------- column partials: per-block 8 rows, coalesced ----------------
__global__ __launch_bounds__(256) void k_colpart(const float* __restrict__ src,
    float* __restrict__ psum, float* __restrict__ psumsq)
{
  int j = blockIdx.x, t = threadIdx.x;
  float s1 = 0.f, s2 = 0.f;
#pragma unroll
  for (int r = 0; r < 8; ++r) {
    float val = src[((size_t)j*8 + r)*256 + t];
    s1 += val;
    s2 += val*val;
  }
  psum[t*64 + j] = s1;
  psumsq[t*64 + j] = s2;
}

// ---------------- memnew = 0.9*mem + 0.1*colmean(hc) ----------------
__global__ __launch_bounds__(256) void k_mem_fin(const float* __restrict__ psum, const float* __restrict__ mem,
                                                 float* __restrict__ memnew)
{
  int t = threadIdx.x;
  float s = 0.f;
  const float* p = psum + t*64;
#pragma unroll 8
  for (int j = 0; j < 64; ++j) s += p[j];
  memnew[t] = 0.9f*mem[t] + 0.1f*(s * (1.f/512.f));
}

__global__ __launch_bounds__(256) void k_x2(const float* __restrict__ hc, const float* __restrict__ memnew,
                                            float* __restrict__ x2)
{
  int i = blockIdx.x*256 + threadIdx.x;
  x2[i] = hc[i] + 0.3f*memnew[i & 255];
}

// ---------------- column stats finalize (am, ainv with ddof=1) ----------------
__global__ __launch_bounds__(256) void k_colstats_fin(const float* __restrict__ psum, const float* __restrict__ psumsq,
                                                       float* __restrict__ am, float* __restrict__ ainv)
{
  int t = threadIdx.x;
  float s1 = 0.f, s2 = 0.f;
  const float* p1 = psum + t*64;
  const float* p2 = psumsq + t*64;
#pragma unroll 8
  for (int j = 0; j < 64; ++j) { s1 += p1[j]; s2 += p2[j]; }
  float mean = s1 * (1.f/512.f);
  float var = fmaxf((s2 - 512.f*mean*mean) * (1.f/511.f), 0.f);
  am[t] = mean;
  ainv[t] = 1.f/(sqrtf(var) + 1e-6f);
}

// ---------------- covariance of standardized features ----------------
__global__ __launch_bounds__(256) void k_cov(const float* __restrict__ hd, const float* __restrict__ am,
    const float* __restrict__ ainv, float* __restrict__ cov)
{
  int i = blockIdx.x, t = threadIdx.x;
  __shared__ float ci[512];
  float ami = am[i], aii = ainv[i];
  for (int b = t; b < 512; b += 256) ci[b] = (hd[(size_t)b*256 + i] - ami)*aii;
  __syncthreads();
  float amj = am[t], aij = ainv[t];
  float acc = 0.f;
  for (int b = 0; b < 512; ++b) acc += ci[b] * (hd[(size_t)b*256 + t] - amj);
  float cval = acc * aij * (1.f/511.f) + ((i == t) ? 1e-4f : 0.f);
  cov[(size_t)i*256 + t] = cval;
}

// ---------------- Householder tridiagonalization — LDS triangle, row-streaming, 16 waves ----------------
// (round-8 measured-best version: wave-uniform segment branches, statically unrolled)
__global__ __launch_bounds__(1024) void k_tridiag(const float* __restrict__ A, float* __restrict__ d, float* __restrict__ e)
{
  const int n = 256;
  __shared__ float tri[32896];
  __shared__ float v[256], q[256];
  __shared__ float ppw[16][257];     // padded: kills stride-256 read conflicts
  __shared__ float redA[4], red4[4];
  __shared__ float sH;
  int t = threadIdx.x;
  int wid = t >> 6, lane = t & 63;

  // load lower triangle from global cov
  for (int i = t; i < 32896; i += 1024) {
    int r = (int)((sqrtf(8.f*(float)i + 1.f) - 1.f) * 0.5f);
    while ((r+1)*(r+2)/2 <= i) ++r;
    while (r*(r+1)/2 > i) --r;
    int c = i - r*(r+1)/2;
    tri[i] = A[(size_t)r*n + c];
  }
  __syncthreads();

  for (int k = 0; k < n-2; ++k) {
    int m = n-1-k;
    int base = k+1;

    // Phase A: gather column k -> v, reduce sigma
    float xi = 0.f;
    if (t < m) {
      int R = base + t;
      xi = tri[R*(R+1)/2 + k];
      v[t] = xi;
    }
    if (t < 256) {
      float val = xi*xi;
#pragma unroll
      for (int mk = 1; mk < 64; mk <<= 1) val += __shfl_xor(val, mk, 64);
      if (lane == 0) redA[wid] = val;
    }
    __syncthreads();                   // B1
    if (t == 0) {
      float sigma = redA[0]+redA[1]+redA[2]+redA[3];
      float x0 = v[0];
      float alpha = (x0 >= 0.f) ? -sqrtf(sigma) : sqrtf(sigma);
      sH = sigma - x0*alpha;
      e[k] = alpha;
      v[0] = x0 - alpha;
    }
    __syncthreads();                   // B2
    float H = sH;
    if (H <= 1e-32f) continue;         // uniform (sH shared)

    // Phase B: row-streaming matvec; per-lane register p-partials (slot c owns index 64c+lane)
    float p0=0.f, p1=0.f, p2=0.f, p3=0.f;
    for (int r = wid; r < m; r += 16) {
      int R = base + r;
      int rowoff = R*(R+1)/2 + base;
      float vr = v[r];
      float dot = 0.f;
#pragma unroll
      for (int c = 0; c < 4; ++c) {
        if (64*c <= r) {
          int j = 64*c + lane;
          float val = (j <= r) ? tri[rowoff + j] : 0.f;
          dot += val * v[j];
          float sval = (j < r) ? val : 0.f;   // diagonal excluded from scatter
          float contrib = sval * vr;
          if (c == 0) p0 += contrib; else if (c == 1) p1 += contrib;
          else if (c == 2) p2 += contrib; else p3 += contrib;
        }
      }
#pragma unroll
      for (int mk = 1; mk < 64; mk <<= 1) dot += __shfl_xor(dot, mk, 64);
      if (lane == (r & 63)) {          // owner lane of p[r] in this wave
        int sl = r >> 6;
        if (sl == 0) p0 += dot; else if (sl == 1) p1 += dot;
        else if (sl == 2) p2 += dot; else p3 += dot;
      }
    }
    ppw[wid][lane]      = p0;
    ppw[wid][64+lane]   = p1;
    ppw[wid][128+lane]  = p2;
    ppw[wid][192+lane]  = p3;
    __syncthreads();                   // B3

    // Phase C: cross-wave p reduce, Kv reduce, q
    float pt = 0.f;
    if (t < 256) {
      float kv = 0.f;
#pragma unroll
      for (int w2 = 0; w2 < 16; ++w2) pt += ppw[w2][t];
      pt /= H;
      if (t < m) kv = v[t] * pt;
#pragma unroll
      for (int mk = 1; mk < 64; mk <<= 1) kv += __shfl_xor(kv, mk, 64);
      if (lane == 0) red4[wid] = kv;
    }
    __syncthreads();                   // B4
    if (t < m) {
      float Kv = (red4[0]+red4[1]+red4[2]+red4[3]) / (2.f*H);
      q[t] = pt - Kv*v[t];
    }
    __syncthreads();                   // B5

    // Phase D: row-streaming rank-2 update (conflict-free consecutive rmw)
    for (int r = wid; r < m; r += 16) {
      int R = base + r;
      int rowoff = R*(R+1)/2 + base;
      float vr = v[r], qr = q[r];
#pragma unroll
      for (int c = 0; c < 4; ++c) {
        if (64*c <= r) {
          int j = 64*c + lane;
          if (j <= r) tri[rowoff + j] -= vr*q[j] + qr*v[j];
        }
      }
    }
    __syncthreads();                   // B6
  }
  if (t == 0) {
    e[n-2] = tri[((n-1)*n)/2 + (n-2)];
    e[n-1] = 0.f;
  }
  if (t < n) d[t] = tri[(t*(t+1))/2 + t];
}

// ---------------- bisection eigenvalues + entropy -> coef ----------------
__global__ __launch_bounds__(256) void k_eig_coef(const float* __restrict__ dg, const float* __restrict__ eg,
                                                  float* __restrict__ coefout)
{
  const int n = 256;
  int t = threadIdx.x;
  __shared__ float sd[256], se2[256], sea[256], red[256];
  sd[t] = dg[t];
  float ev = (t < n-1) ? eg[t] : 0.f;
  se2[t] = ev*ev;
  sea[t] = fabsf(ev);
  __syncthreads();
  float r = ((t > 0) ? sea[t-1] : 0.f) + sea[t];
  red[t] = sd[t] - r; __syncthreads();
  for (int s = 128; s > 0; s >>= 1) { if (t < s) red[t] = fminf(red[t], red[t+s]); __syncthreads(); }
  float glo = red[0] - 1e-3f; __syncthreads();
  red[t] = sd[t] + r; __syncthreads();
  for (int s = 128; s > 0; s >>= 1) { if (t < s) red[t] = fmaxf(red[t], red[t+s]); __syncthreads(); }
  float ghi = red[0] + 1e-3f; __syncthreads();

  float lo = glo, hi = ghi;
  for (int it = 0; it < 28; ++it) {
    float mid = 0.5f*(lo + hi);
    int cnt = 0;
    float qq = sd[0] - mid;
    cnt += (qq < 0.f);
    for (int i = 1; i < n; ++i) {
      float denom = qq;
      if (fabsf(denom) < 1e-20f) denom = (denom < 0.f) ? -1e-20f : 1e-20f;
      qq = sd[i] - mid - se2[i-1]/denom;
      cnt += (qq < 0.f);
    }
    if (cnt <= t) lo = mid; else hi = mid;
  }
  float lam = fmaxf(0.5f*(lo + hi), 0.f);
  float tot = block_sum<256>(lam, red, t) + 1e-8f;
  float en = lam / tot;
  float contrib = -en * logf(en + 1e-8f);
  float ent = block_sum<256>(contrib, red, t);
  if (t == 0) {
    float phi = ent / logf(256.f);
    float phi_eff = fminf(fmaxf(0.3f*phi, 0.f), 1.f);
    float strength = 1.f/(1.f + expf(-(phi_eff - 0.1f)*5.f));
    coefout[0] = (phi_eff > 0.1f) ? strength : 0.1f;
  }
}

// ---------------- fused consciousness net: t1 = relu(LN(hd@W1+b1)); hcon = hd + coef*(t1@W2+b2) ----------------
__global__ __launch_bounds__(256) void k_cn(const float* __restrict__ hd, const float* __restrict__ W1,
    const float* __restrict__ b1, const float* __restrict__ g, const float* __restrict__ be,
    const float* __restrict__ W2, const float* __restrict__ b2, const float* __restrict__ coefp,
    float* __restrict__ hcon)
{
  __shared__ float xs[256];
  __shared__ float t1s[256];
  __shared__ float red[256];
  int b = blockIdx.x, t = threadIdx.x;
  xs[t] = hd[(size_t)b*256 + t];
  __syncthreads();
  float acc = dot_f32_row<256>(W1 + (size_t)t*256, xs) + b1[t];
  float mean = block_sum<256>(acc, red, t) * (1.f/256.f);
  float dv = acc - mean;
  float var = block_sum<256>(dv*dv, red, t) * (1.f/256.f);
  t1s[t] = fmaxf(dv * rsqrtf(var + 1e-5f) * g[t] + be[t], 0.f);
  __syncthreads();
  float acc2 = dot_f32_row<256>(W2 + (size_t)t*256, t1s) + b2[t];
  hcon[(size_t)b*256 + t] = xs[t] + coefp[0]*acc2;
}

// ---------------- fused projection + classifier ----------------
__global__ __launch_bounds__(128) void k_pr_cls(const float* __restrict__ hcon, const float* __restrict__ W,
    const float* __restrict__ bias, const float* __restrict__ g, const float* __restrict__ be,
    const float* __restrict__ Wc, const float* __restrict__ bc, float* __restrict__ out)
{
  __shared__ float xs[256];
  __shared__ float hp[128];
  __shared__ float red[128];
  int b = blockIdx.x, t = threadIdx.x;
  xs[t] = hcon[(size_t)b*256 + t];
  xs[t+128] = hcon[(size_t)b*256 + t + 128];
  __syncthreads();
  float acc = dot_f32_row<256>(W + (size_t)t*256, xs) + bias[t];
  float mean = block_sum<128>(acc, red, t) * (1.f/128.f);
  float dv = acc - mean;
  float var = block_sum<128>(dv*dv, red, t) * (1.f/128.f);
  hp[t] = fmaxf(dv * rsqrtf(var + 1e-5f) * g[t] + be[t], 0.f);
  __syncthreads();
  if (t < 10) {
    float a2 = bc[t];
    const float* wr = Wc + (size_t)t*128;
    for (int i = 0; i < 128; ++i) a2 += wr[i]*hp[i];
    out[(size_t)b*10 + t] = a2;
  }
}

// ================= host launcher =================
extern "C" void kernel_launch(void* const* d_in, const int* in_sizes, int n_in,
                              void* d_out, int out_size, void* d_ws, size_t ws_size,
                              hipStream_t stream)
{
  (void)in_sizes; (void)n_in; (void)out_size; (void)ws_size;
  const float* x     = (const float*)d_in[0];
  const float* c1w   = (const float*)d_in[1];
  const float* c1b   = (const float*)d_in[2];
  const float* bn1g  = (const float*)d_in[3];
  const float* bn1b  = (const float*)d_in[4];
  const float* bn1m  = (const float*)d_in[5];
  const float* bn1v  = (const float*)d_in[6];
  const float* c2w   = (const float*)d_in[7];
  const float* c2b   = (const float*)d_in[8];
  const float* bn2g  = (const float*)d_in[9];
  const float* bn2b  = (const float*)d_in[10];
  const float* bn2m  = (const float*)d_in[11];
  const float* bn2v  = (const float*)d_in[12];
  const float* c3w   = (const float*)d_in[13];
  const float* c3b   = (const float*)d_in[14];
  const float* bn3g  = (const float*)d_in[15];
  const float* bn3b  = (const float*)d_in[16];
  const float* bn3m  = (const float*)d_in[17];
  const float* bn3v  = (const float*)d_in[18];
  const float* corew = (const float*)d_in[19];
  const float* coreb = (const float*)d_in[20];
  const float* corelng = (const float*)d_in[21];
  const float* corelnb = (const float*)d_in[22];
  const float* fpsw  = (const float*)d_in[23];
  const float* fpsb  = (const float*)d_in[24];
  const float* fpfw  = (const float*)d_in[25];
  const float* fpfb  = (const float*)d_in[26];
  const float* fplng = (const float*)d_in[27];
  const float* fplnb = (const float*)d_in[28];
  const float* spsw  = (const float*)d_in[29];
  const float* spsb  = (const float*)d_in[30];
  const float* spfw  = (const float*)d_in[31];
  const float* spfb  = (const float*)d_in[32];
  const float* splng = (const float*)d_in[33];
  const float* splnb = (const float*)d_in[34];
  const float* intw  = (const float*)d_in[35];
  const float* intb  = (const float*)d_in[36];
  const float* intlng= (const float*)d_in[37];
  const float* intlnb= (const float*)d_in[38];
  const float* memi  = (const float*)d_in[39];
  const float* cnw1  = (const float*)d_in[40];
  const float* cnb1  = (const float*)d_in[41];
  const float* cnlng = (const float*)d_in[42];
  const float* cnlnb = (const float*)d_in[43];
  const float* cnw2  = (const float*)d_in[44];
  const float* cnb2  = (const float*)d_in[45];
  const float* prw   = (const float*)d_in[46];
  const float* prb   = (const float*)d_in[47];
  const float* prlng = (const float*)d_in[48];
  const float* prlnb = (const float*)d_in[49];
  const float* clw   = (const float*)d_in[50];
  const float* clb   = (const float*)d_in[51];
  float* out = (float*)d_out;

  float* w = (float*)d_ws;
  size_t off = 0;
  auto alloc = [&](size_t nel) { float* p = w + off; off += nel; return p; };
  float* p1     = alloc((size_t)512*64*16*16);
  float* p2     = alloc((size_t)512*128*8*8);
  float* h      = alloc(512*256);
  float* hc     = alloc(512*256);
  float* x2     = alloc(512*256);
  float* s      = alloc(512*256);
  float* xninv  = alloc(512);
  float* sninv  = alloc(512);
  float* memnew = alloc(256);
  float* weff   = alloc(256*256);
  float* beff   = alloc(256);
  float* comb   = alloc((size_t)512*512);
  float* hd     = alloc(512*256);
  float* am     = alloc(256);
  float* ainv   = alloc(256);
  float* cov    = alloc(256*256);
  float* dvec   = alloc(256);
  float* evec   = alloc(256);
  float* coefb  = alloc(8);
  float* hcon   = alloc(512*256);
  float* psum   = alloc(256*64);
  float* psumsq = alloc(256*64);

  // encoder
  k_conv1<<<512,256,0,stream>>>(x, c1w, c1b, bn1g, bn1b, bn1m, bn1v, p1);
  k_conv2<<<512,256,0,stream>>>(p1, c2w, c2b, bn2g, bn2b, bn2m, bn2v, p2);
  k_conv3<<<512,256,0,stream>>>(p2, c3w, c3b, bn3g, bn3b, bn3m, bn3v, h);
  // core
  k_lin_ln<256,256,true,false><<<512,256,0,stream>>>(h, corew, coreb, corelng, corelnb, nullptr, hc, 256, 0);
  // memory EMA (parallel column mean) + slow-path input
  k_colpart<<<64,256,0,stream>>>(hc, psum, psumsq);
  k_mem_fin<<<1,256,0,stream>>>(psum, memi, memnew);
  k_x2<<<512,256,0,stream>>>(hc, memnew, x2);
  // fast path (lr=0.015, decay=0.95)
  k_lin_rownorm<<<512,256,0,stream>>>(hc, fpsw, fpsb, s, xninv, sninv);
  k_hebb<<<256,256,0,stream>>>(hc, s, xninv, sninv, fpsw, fpfw, fpsb, fpfb, 0.015f, 0.95f, weff, beff);
  k_lin_ln<256,256,false,false><<<512,256,0,stream>>>(hc, weff, beff, fplng, fplnb, nullptr, comb, 512, 0);
  // slow path (lr=0.005, decay=0.97)
  k_lin_rownorm<<<512,256,0,stream>>>(x2, spsw, spsb, s, xninv, sninv);
  k_hebb<<<256,256,0,stream>>>(x2, s, xninv, sninv, spsw, spfw, spsb, spfb, 0.005f, 0.97f, weff, beff);
  k_lin_ln<256,256,false,false><<<512,256,0,stream>>>(x2, weff, beff, splng, splnb, nullptr, comb, 512, 256);
  // integrator + residual
  k_lin_ln<512,256,false,true><<<512,256,0,stream>>>(comb, intw, intb, intlng, intlnb, hc, hd, 256, 0);
  // consciousness stats (parallel)
  k_colpart<<<64,256,0,stream>>>(hd, psum, psumsq);
  k_colstats_fin<<<1,256,0,stream>>>(psum, psumsq, am, ainv);
  k_cov<<<256,256,0,stream>>>(hd, am, ainv, cov);
  k_tridiag<<<1,1024,0,stream>>>(cov, dvec, evec);
  k_eig_coef<<<1,256,0,stream>>>(dvec, evec, coefb);
  // consciousness net + gated residual (fused)
  k_cn<<<512,256,0,stream>>>(hd, cnw1, cnb1, cnlng, cnlnb, cnw2, cnb2, coefb, hcon);
  // projection + classifier (fused)
  k_pr_cls<<<512,128,0,stream>>>(hcon, prw, prb, prlng, prlnb, clw, clb, out);
}